// Round 4
// baseline (2594.473 us; speedup 1.0000x reference)
//
#include <hip/hip_runtime.h>
#include <math.h>

typedef short bf16x8 __attribute__((ext_vector_type(8)));
typedef float f32x4 __attribute__((ext_vector_type(4)));
typedef unsigned short u16;
typedef unsigned int u32;

#define B_    32
#define D_    384
#define DEPTH 12
#define NST   16
#define DI_   768
#define R_    24
#define L_    196
#define NC_   1000
#define M_    (B_*L_)   // 6272
#define SCH   32        // scan chunk length

__device__ __forceinline__ u16 f2bf(float f) {
  union { float f; unsigned u; } v; v.f = f;
  unsigned r = v.u + 0x7fffu + ((v.u >> 16) & 1u);
  return (u16)(r >> 16);
}

// ---------------- weight prep ----------------
__global__ void k_transpose_bf16(const float* __restrict__ in, u16* __restrict__ out,
                                 int R, int C) {
  __shared__ float tile[32][33];
  const size_t zoff = (size_t)blockIdx.z * R * C;
  in  += zoff; out += zoff;
  int c0 = blockIdx.x * 32, r0 = blockIdx.y * 32;
  int tx = threadIdx.x, ty = threadIdx.y;
  for (int i = ty; i < 32; i += 8) {
    int r = r0 + i, c = c0 + tx;
    tile[i][tx] = (r < R && c < C) ? in[(size_t)r * C + c] : 0.f;
  }
  __syncthreads();
  for (int i = ty; i < 32; i += 8) {
    int c = c0 + i, r = r0 + tx;
    if (c < C && r < R) out[(size_t)c * R + r] = f2bf(tile[tx][i]);
  }
}

__global__ void k_convert_bf16(const float* __restrict__ in, u16* __restrict__ out, int n) {
  int i = blockIdx.x * 256 + threadIdx.x;
  if (i < n) out[i] = f2bf(in[i]);
}

// ---------------- im2col for patch embed ----------------
__global__ void k_im2col(const float* __restrict__ x, u16* __restrict__ xcol) {
  int idx = blockIdx.x * 256 + threadIdx.x;     // over M_*768
  if (idx >= M_ * 768) return;
  int k = idx % 768, m = idx / 768;
  int b = m / L_, l = m % L_;
  int li = l / 14, lj = l % 14;
  int c = k / 256, r = k % 256;
  int i = r / 16, j = r % 16;
  int hh = li * 16 + i, ww = lj * 16 + j;
  xcol[idx] = f2bf(x[(((size_t)b * 3 + c) * 224 + hh) * 224 + ww]);
}

// ---------------- GEMM: C(MxN) = A(MxK,bf16) * BT(NxK,bf16)^T ----------------
// EPI: 0 = store, 1 = add (residual), 2 = store + bias[col] + pos[(row%L)*N+col]
template<int BM, int BN, int EPI>
__global__ __launch_bounds__(256)
void k_gemm(const u16* __restrict__ A, const u16* __restrict__ BT,
            float* __restrict__ Cout, int Nn, int Kk,
            const float* __restrict__ bias, const float* __restrict__ pos) {
  const int m0 = blockIdx.x * BM;
  const int n0 = blockIdx.y * BN;
  __shared__ u16 lA[BM * 72];
  __shared__ u16 lB[BN * 72];
  const int tid  = threadIdx.x;
  const int wave = tid >> 6, lane = tid & 63;
  const int wm = (wave >> 1) * (BM / 2), wn = (wave & 1) * (BN / 2);
  constexpr int MI = BM / 32, NJ = BN / 32;
  constexpr int NV = (BM + BN) / 32;     // bf16x8 loads per thread per k-chunk
  f32x4 acc[MI][NJ] = {};
  const int fr = lane & 15, kg = (lane >> 4) * 8;

  for (int k0 = 0; k0 < Kk; k0 += 64) {
    bf16x8 v[NV];
    #pragma unroll
    for (int q = 0; q < NV; ++q) {
      int id = tid + q * 256;
      int row = id >> 3, vv = id & 7;
      bf16x8 t = {};
      if (row < BM) {
        t = *(const bf16x8*)(A + (size_t)(m0 + row) * Kk + k0 + vv * 8);
      } else {
        int br = n0 + row - BM;
        if (br < Nn) t = *(const bf16x8*)(BT + (size_t)br * Kk + k0 + vv * 8);
      }
      v[q] = t;
    }
    __syncthreads();
    #pragma unroll
    for (int q = 0; q < NV; ++q) {
      int id = tid + q * 256;
      int row = id >> 3, vv = id & 7;
      u16* dst = (row < BM) ? (lA + row * 72 + vv * 8) : (lB + (size_t)(row - BM) * 72 + vv * 8);
      *(bf16x8*)dst = v[q];
    }
    __syncthreads();
    #pragma unroll
    for (int kk = 0; kk < 64; kk += 32) {
      bf16x8 af[MI], bfr[NJ];
      #pragma unroll
      for (int i = 0; i < MI; ++i)
        af[i] = *(const bf16x8*)(lA + (wm + i * 16 + fr) * 72 + kk + kg);
      #pragma unroll
      for (int j = 0; j < NJ; ++j)
        bfr[j] = *(const bf16x8*)(lB + (wn + j * 16 + fr) * 72 + kk + kg);
      #pragma unroll
      for (int i = 0; i < MI; ++i)
        #pragma unroll
        for (int j = 0; j < NJ; ++j)
          acc[i][j] = __builtin_amdgcn_mfma_f32_16x16x32_bf16(af[i], bfr[j], acc[i][j], 0, 0, 0);
    }
  }

  const int rg = (lane >> 4) * 4;
  #pragma unroll
  for (int i = 0; i < MI; ++i) {
    int row = m0 + wm + i * 16 + rg;
    #pragma unroll
    for (int j = 0; j < NJ; ++j) {
      int col = n0 + wn + j * 16 + fr;
      if (col >= Nn) continue;
      #pragma unroll
      for (int r = 0; r < 4; ++r) {
        float v = acc[i][j][r];
        size_t idx = (size_t)(row + r) * Nn + col;
        if (EPI == 0)      Cout[idx] = v;
        else if (EPI == 1) Cout[idx] += v;
        else               Cout[idx] = v + bias[col] + pos[(size_t)((row + r) % L_) * Nn + col];
      }
    }
  }
}

// ---------------- LayerNorm (writes bf16 for GEMM A) ----------------
__global__ __launch_bounds__(384)
void k_ln(const float* __restrict__ x, const float* __restrict__ g,
          const float* __restrict__ bt, u16* __restrict__ h) {
  const int m = blockIdx.x, d = threadIdx.x;
  __shared__ float red[12];
  float v = x[(size_t)m * D_ + d];
  float s = v, s2 = v * v;
  #pragma unroll
  for (int o = 32; o > 0; o >>= 1) { s += __shfl_xor(s, o); s2 += __shfl_xor(s2, o); }
  int wid = d >> 6;
  if ((d & 63) == 0) { red[wid] = s; red[6 + wid] = s2; }
  __syncthreads();
  float ts = 0.f, ts2 = 0.f;
  #pragma unroll
  for (int w = 0; w < 6; ++w) { ts += red[w]; ts2 += red[6 + w]; }
  float mu = ts / (float)D_;
  float var = ts2 / (float)D_ - mu * mu;
  float rs = rsqrtf(var + 1e-5f);
  h[(size_t)m * D_ + d] = f2bf((v - mu) * rs * g[d] + bt[d]);
}

// ---------------- causal depthwise conv (K=4) + SiLU ----------------
__global__ __launch_bounds__(256)
void k_conv(const float* __restrict__ xz, const float* __restrict__ cw,
            const float* __restrict__ cb, float* __restrict__ xc, u16* __restrict__ xcb) {
  int idx = blockIdx.x * 256 + threadIdx.x;   // over M_*DI_
  if (idx >= M_ * DI_) return;
  int di = idx % DI_, m = idx / DI_, l = m % L_;
  float w0 = cw[di * 4 + 0], w1 = cw[di * 4 + 1], w2 = cw[di * 4 + 2], w3 = cw[di * 4 + 3];
  const float* base = xz + (size_t)m * 1536 + di;
  float acc = cb[di] + w3 * base[0];
  if (l >= 1) acc += w2 * base[-1536];
  if (l >= 2) acc += w1 * base[-2 * 1536];
  if (l >= 3) acc += w0 * base[-3 * 1536];
  float s = acc / (1.f + __expf(-acc));       // silu
  xc[idx] = s;
  xcb[idx] = f2bf(s);
}

// ---------------- dt = softplus(dbc[:, :24] @ dtp_w + dtp_b) ----------------
__global__ __launch_bounds__(256)
void k_dt(const float* __restrict__ dbc, const float* __restrict__ dtw,
          const float* __restrict__ dtb, float* __restrict__ dt) {
  const int m0 = blockIdx.x * 16;
  const int di = blockIdx.y * 256 + threadIdx.x;
  __shared__ float sd[16][25];
  #pragma unroll
  for (int q = 0; q < 2; ++q) {
    int id = threadIdx.x + q * 256;
    if (id < 16 * 24) {
      int r = id / 24, c = id % 24;
      sd[r][c] = dbc[(size_t)(m0 + r) * 56 + c];
    }
  }
  __syncthreads();
  float w[24];
  #pragma unroll
  for (int r = 0; r < 24; ++r) w[r] = dtw[r * DI_ + di];
  const float bv = dtb[di];
  #pragma unroll 4
  for (int mi = 0; mi < 16; ++mi) {
    float acc = bv;
    #pragma unroll
    for (int r = 0; r < 24; ++r) acc += sd[mi][r] * w[r];
    float e  = __expf(-fabsf(acc));
    float sp = fmaxf(acc, 0.f) + __logf(1.f + e);
    dt[(size_t)(m0 + mi) * DI_ + di] = sp;
  }
}

// ---------------- selective scan v3: 16 threads per channel (1 per state) ----------------
// grid (B_, DI_/16) = (32,48) = 1536 blocks, block 256 = 16 di x 16 states.
// 6 blocks/CU -> 24 waves/CU (4x the TLP of v2). h = 1 reg/thread.
__global__ __launch_bounds__(256, 6)
void k_scan(const float* __restrict__ dbc, const float* __restrict__ dt,
            const float* __restrict__ xc, const float* __restrict__ xz,
            const float* __restrict__ A_log, const float* __restrict__ Dsk,
            u16* __restrict__ yb) {
  const int b   = blockIdx.x;
  const int di0 = blockIdx.y * 16;
  const int tid = threadIdx.x;
  const int dil = tid >> 4, nst = tid & 15;
  const int di  = di0 + dil;
  __shared__ float sDT[2][SCH][16];
  __shared__ float sXC[2][SCH][16];
  __shared__ float sZ [2][SCH][16];
  __shared__ float sBC[2][SCH][32];
  __shared__ u16  sY [SCH][16];

  // A_log[di*NST + nst] = A_log[di0*16 + tid]  (contiguous per block)
  const float Ae = -__expf(A_log[di0 * NST + tid]);
  const float Dv = Dsk[di];
  float h = 0.f;
  const size_t mb = (size_t)b * L_;

  // staging roles: half 0 loads dt+z, half 1 loads xc; all load BC
  const int half = tid >> 7;
  const int hid  = tid & 127;
  const int rA = hid >> 2, cA = (hid & 3) * 4;   // 32 rows x 16 cols
  const int rB = tid >> 3, cB = (tid & 7) * 4;   // 32 rows x 32 cols

  f32x4 pA, pZ, pBC;
  auto issue = [&](int lb) {
    int l = lb + rA;
    bool ok = l < L_;
    if (half == 0) {
      pA = ok ? *(const f32x4*)(dt + (mb + l) * DI_ + di0 + cA) : f32x4{};
      pZ = ok ? *(const f32x4*)(xz + (mb + l) * 1536 + DI_ + di0 + cA) : f32x4{};
    } else {
      pA = ok ? *(const f32x4*)(xc + (mb + l) * DI_ + di0 + cA) : f32x4{};
    }
    int lB = lb + rB;
    pBC = (lB < L_) ? *(const f32x4*)(dbc + (mb + lB) * 56 + 24 + cB) : f32x4{};
  };
  auto store = [&](int buf) {
    if (half == 0) {
      *(f32x4*)&sDT[buf][rA][cA] = pA;
      *(f32x4*)&sZ [buf][rA][cA] = pZ;
    } else {
      *(f32x4*)&sXC[buf][rA][cA] = pA;
    }
    *(f32x4*)&sBC[buf][rB][cB] = pBC;
  };

  issue(0); store(0); __syncthreads();
  const int nch = (L_ + SCH - 1) / SCH;   // 7
  for (int c = 0; c < nch; ++c) {
    const int lb = c * SCH;
    if (c + 1 < nch) issue(lb + SCH);     // next-chunk loads fly during compute
    const int cur = c & 1;
    #pragma unroll 4
    for (int t = 0; t < SCH; ++t) {
      float dtc = sDT[cur][t][dil];
      float xcc = sXC[cur][t][dil];
      float e = __expf(dtc * Ae);
      h = e * h + (dtc * xcc) * sBC[cur][t][nst];
      float y = h * sBC[cur][t][16 + nst];
      y += __shfl_xor(y, 1);
      y += __shfl_xor(y, 2);
      y += __shfl_xor(y, 4);
      y += __shfl_xor(y, 8);
      if (nst == 0) {
        float zc = sZ[cur][t][dil];
        float sz = zc / (1.f + __expf(-zc));
        sY[t][dil] = f2bf((y + Dv * xcc) * sz);
      }
    }
    __syncthreads();
    {
      int row = tid >> 3, c2 = tid & 7;   // 32 rows x 8 u32 (16 u16)
      int l = lb + row;
      if (l < L_)
        *((u32*)yb + ((mb + l) * DI_ + di0) / 2 + c2) = *((const u32*)&sY[row][0] + c2);
    }
    if (c + 1 < nch) store((c + 1) & 1);
    __syncthreads();
  }
}

// ---------------- final LN partial sums: grid (B_, 7), 28 rows each ----------------
__global__ __launch_bounds__(384)
void k_feat_part(const float* __restrict__ x, float* __restrict__ partial) {
  const int b = blockIdx.x, j = blockIdx.y, d = threadIdx.x;
  __shared__ float red[12];
  const int l0 = j * 28;
  float acc = 0.f;
  float v = x[((size_t)b * L_ + l0) * D_ + d];
  for (int l = l0; l < l0 + 28; ++l) {
    float vn = (l + 1 < l0 + 28) ? x[((size_t)b * L_ + l + 1) * D_ + d] : 0.f;
    float s = v, s2 = v * v;
    #pragma unroll
    for (int o = 32; o > 0; o >>= 1) { s += __shfl_xor(s, o); s2 += __shfl_xor(s2, o); }
    int wid = d >> 6;
    if ((d & 63) == 0) { red[wid] = s; red[6 + wid] = s2; }
    __syncthreads();
    float ts = 0.f, ts2 = 0.f;
    #pragma unroll
    for (int w = 0; w < 6; ++w) { ts += red[w]; ts2 += red[6 + w]; }
    float mu = ts * (1.f / (float)D_);
    float var = ts2 * (1.f / (float)D_) - mu * mu;
    acc += (v - mu) * rsqrtf(var + 1e-5f);
    __syncthreads();
    v = vn;
  }
  partial[((size_t)(b * 7 + j)) * D_ + d] = acc;
}

// ---------------- head (folds final-LN gamma/beta + mean) ----------------
__global__ __launch_bounds__(256)
void k_head(const float* __restrict__ partial, const float* __restrict__ g,
            const float* __restrict__ bt, const float* __restrict__ hw,
            const float* __restrict__ hb, float* __restrict__ out) {
  const int b = blockIdx.y;
  const int c = blockIdx.x * 256 + threadIdx.x;
  __shared__ float sf[D_];
  for (int i = threadIdx.x; i < D_; i += 256) {
    float s = 0.f;
    #pragma unroll
    for (int j = 0; j < 7; ++j) s += partial[((size_t)(b * 7 + j)) * D_ + i];
    sf[i] = g[i] * (s * (1.f / (float)L_)) + bt[i];
  }
  __syncthreads();
  if (c >= NC_) return;
  float acc = hb[c];
  for (int d = 0; d < D_; ++d) acc += sf[d] * hw[(size_t)d * NC_ + c];
  out[(size_t)b * NC_ + c] = acc;
}

// =====================================================================
extern "C" void kernel_launch(void* const* d_in, const int* in_sizes, int n_in,
                              void* d_out, int out_size, void* d_ws, size_t ws_size,
                              hipStream_t stream) {
  const float* x_in    = (const float*)d_in[0];
  const float* patch_w = (const float*)d_in[1];
  const float* patch_b = (const float*)d_in[2];
  const float* pos     = (const float*)d_in[3];
  const float* bn_g    = (const float*)d_in[4];
  const float* bn_b    = (const float*)d_in[5];
  const float* in_w    = (const float*)d_in[6];
  const float* conv_w  = (const float*)d_in[7];
  const float* conv_b  = (const float*)d_in[8];
  const float* xp_w    = (const float*)d_in[9];
  const float* dtp_w   = (const float*)d_in[10];
  const float* dtp_b   = (const float*)d_in[11];
  const float* A_log   = (const float*)d_in[12];
  const float* D_skip  = (const float*)d_in[13];
  const float* out_w   = (const float*)d_in[14];
  const float* norm_g  = (const float*)d_in[15];
  const float* norm_b  = (const float*)d_in[16];
  const float* head_w  = (const float*)d_in[17];
  const float* head_b  = (const float*)d_in[18];
  float* out = (float*)d_out;

  char* ws = (char*)d_ws;
  size_t off = 0;
  auto alloc = [&](size_t bytes) { size_t o = off; off += (bytes + 255) & ~(size_t)255; return o; };

  float* xbuf   = (float*)(ws + alloc((size_t)M_ * D_ * 4));
  u16*   hbuf   = (u16*)  (ws + alloc((size_t)M_ * D_ * 2));
  float* xzbuf  = (float*)(ws + alloc((size_t)M_ * 1536 * 4));
  float* xcbuf  = (float*)(ws + alloc((size_t)M_ * DI_ * 4));
  u16*   xcbb   = (u16*)  (ws + alloc((size_t)M_ * DI_ * 2));
  float* dbcbuf = (float*)(ws + alloc((size_t)M_ * 56 * 4));
  float* dtbuf  = (float*)(ws + alloc((size_t)M_ * DI_ * 4));   // aliased as im2col before loop
  u16*   ybuf   = (u16*)  (ws + alloc((size_t)M_ * DI_ * 2));
  float* partial= (float*)(ws + alloc((size_t)B_ * 7 * D_ * 4));
  u16*   in_wT  = (u16*)  (ws + alloc((size_t)DEPTH * 1536 * D_ * 2));
  u16*   xp_wT  = (u16*)  (ws + alloc((size_t)DEPTH * 56 * DI_ * 2));
  u16*   out_wT = (u16*)  (ws + alloc((size_t)DEPTH * D_ * DI_ * 2));
  u16*   pw_b   = (u16*)  (ws + alloc((size_t)D_ * 768 * 2));
  u16*   im2col = (u16*)dtbuf;

  dim3 tb(32, 8);
  k_transpose_bf16<<<dim3(48, 12, DEPTH), tb, 0, stream>>>(in_w,  in_wT,  D_, 1536);
  k_transpose_bf16<<<dim3(2, 24, DEPTH),  tb, 0, stream>>>(xp_w,  xp_wT,  DI_, 56);
  k_transpose_bf16<<<dim3(12, 24, DEPTH), tb, 0, stream>>>(out_w, out_wT, DI_, D_);
  k_convert_bf16<<<(D_ * 768 + 255) / 256, 256, 0, stream>>>(patch_w, pw_b, D_ * 768);

  k_im2col<<<(M_ * 768 + 255) / 256, 256, 0, stream>>>(x_in, im2col);
  k_gemm<64,128,2><<<dim3(M_ / 64, 3), 256, 0, stream>>>(im2col, pw_b, xbuf, D_, 768, patch_b, pos);

  for (int dp = 0; dp < DEPTH; ++dp) {
    const u16* iwt = in_wT  + (size_t)dp * 1536 * D_;
    const u16* xwt = xp_wT  + (size_t)dp * 56 * DI_;
    const u16* owt = out_wT + (size_t)dp * D_ * DI_;
    k_ln<<<M_, 384, 0, stream>>>(xbuf, bn_g + dp * D_, bn_b + dp * D_, hbuf);
    k_gemm<128,128,0><<<dim3(M_ / 128, 12), 256, 0, stream>>>(hbuf, iwt, xzbuf, 1536, D_, nullptr, nullptr);
    k_conv<<<(M_ * DI_ + 255) / 256, 256, 0, stream>>>(xzbuf, conv_w + (size_t)dp * DI_ * 4,
                                                       conv_b + dp * DI_, xcbuf, xcbb);
    k_gemm<32,64,0><<<dim3(M_ / 32, 1), 256, 0, stream>>>(xcbb, xwt, dbcbuf, 56, DI_, nullptr, nullptr);
    k_dt<<<dim3(M_ / 16, DI_ / 256), 256, 0, stream>>>(dbcbuf, dtp_w + (size_t)dp * R_ * DI_,
                                                       dtp_b + dp * DI_, dtbuf);
    k_scan<<<dim3(B_, DI_ / 16), 256, 0, stream>>>(dbcbuf, dtbuf, xcbuf, xzbuf,
                                                   A_log + (size_t)dp * DI_ * NST,
                                                   D_skip + dp * DI_, ybuf);
    k_gemm<64,128,1><<<dim3(M_ / 64, 3), 256, 0, stream>>>(ybuf, owt, xbuf, D_, DI_, nullptr, nullptr);
  }

  k_feat_part<<<dim3(B_, 7), 384, 0, stream>>>(xbuf, partial);
  k_head<<<dim3((NC_ + 255) / 256, B_), 256, 0, stream>>>(partial, norm_g, norm_b, head_w, head_b, out);
}

// Round 5
// 1906.151 us; speedup vs baseline: 1.3611x; 1.3611x over previous
//
#include <hip/hip_runtime.h>
#include <math.h>

typedef short bf16x8 __attribute__((ext_vector_type(8)));
typedef float f32x4 __attribute__((ext_vector_type(4)));
typedef unsigned short u16;
typedef unsigned int u32;
typedef unsigned short u16x4 __attribute__((ext_vector_type(4)));

#define B_    32
#define D_    384
#define DEPTH 12
#define NST   16
#define DI_   768
#define R_    24
#define L_    196
#define NC_   1000
#define M_    (B_*L_)   // 6272
#define SCH   32        // scan chunk length

__device__ __forceinline__ u16 f2bf(float f) {
  union { float f; unsigned u; } v; v.f = f;
  unsigned r = v.u + 0x7fffu + ((v.u >> 16) & 1u);
  return (u16)(r >> 16);
}
__device__ __forceinline__ float bf2f(u16 x) {
  union { unsigned u; float f; } v; v.u = ((unsigned)x) << 16;
  return v.f;
}

// ---------------- weight prep ----------------
__global__ void k_transpose_bf16(const float* __restrict__ in, u16* __restrict__ out,
                                 int R, int C) {
  __shared__ float tile[32][33];
  const size_t zoff = (size_t)blockIdx.z * R * C;
  in  += zoff; out += zoff;
  int c0 = blockIdx.x * 32, r0 = blockIdx.y * 32;
  int tx = threadIdx.x, ty = threadIdx.y;
  for (int i = ty; i < 32; i += 8) {
    int r = r0 + i, c = c0 + tx;
    tile[i][tx] = (r < R && c < C) ? in[(size_t)r * C + c] : 0.f;
  }
  __syncthreads();
  for (int i = ty; i < 32; i += 8) {
    int c = c0 + i, r = r0 + tx;
    if (c < C && r < R) out[(size_t)c * R + r] = f2bf(tile[tx][i]);
  }
}

__global__ void k_convert_bf16(const float* __restrict__ in, u16* __restrict__ out, int n) {
  int i = blockIdx.x * 256 + threadIdx.x;
  if (i < n) out[i] = f2bf(in[i]);
}

// ---------------- im2col for patch embed ----------------
__global__ void k_im2col(const float* __restrict__ x, u16* __restrict__ xcol) {
  int idx = blockIdx.x * 256 + threadIdx.x;     // over M_*768
  if (idx >= M_ * 768) return;
  int k = idx % 768, m = idx / 768;
  int b = m / L_, l = m % L_;
  int li = l / 14, lj = l % 14;
  int c = k / 256, r = k % 256;
  int i = r / 16, j = r % 16;
  int hh = li * 16 + i, ww = lj * 16 + j;
  xcol[idx] = f2bf(x[(((size_t)b * 3 + c) * 224 + hh) * 224 + ww]);
}

// ---------------- GEMM: C(MxN) = A(MxK,bf16) * BT(NxK,bf16)^T ----------------
// EPI: 0 = store, 1 = add (residual), 2 = store + bias[col] + pos[(row%L)*N+col]
// OB:  1 = store bf16 (u16) instead of f32 (EPI==0 only)
template<int BM, int BN, int EPI, int OB>
__global__ __launch_bounds__(256)
void k_gemm(const u16* __restrict__ A, const u16* __restrict__ BT,
            float* __restrict__ Cout, int Nn, int Kk,
            const float* __restrict__ bias, const float* __restrict__ pos) {
  const int m0 = blockIdx.x * BM;
  const int n0 = blockIdx.y * BN;
  __shared__ u16 lA[BM * 72];
  __shared__ u16 lB[BN * 72];
  const int tid  = threadIdx.x;
  const int wave = tid >> 6, lane = tid & 63;
  const int wm = (wave >> 1) * (BM / 2), wn = (wave & 1) * (BN / 2);
  constexpr int MI = BM / 32, NJ = BN / 32;
  constexpr int NV = (BM + BN) / 32;     // bf16x8 loads per thread per k-chunk
  f32x4 acc[MI][NJ] = {};
  const int fr = lane & 15, kg = (lane >> 4) * 8;

  for (int k0 = 0; k0 < Kk; k0 += 64) {
    bf16x8 v[NV];
    #pragma unroll
    for (int q = 0; q < NV; ++q) {
      int id = tid + q * 256;
      int row = id >> 3, vv = id & 7;
      bf16x8 t = {};
      if (row < BM) {
        t = *(const bf16x8*)(A + (size_t)(m0 + row) * Kk + k0 + vv * 8);
      } else {
        int br = n0 + row - BM;
        if (br < Nn) t = *(const bf16x8*)(BT + (size_t)br * Kk + k0 + vv * 8);
      }
      v[q] = t;
    }
    __syncthreads();
    #pragma unroll
    for (int q = 0; q < NV; ++q) {
      int id = tid + q * 256;
      int row = id >> 3, vv = id & 7;
      u16* dst = (row < BM) ? (lA + row * 72 + vv * 8) : (lB + (size_t)(row - BM) * 72 + vv * 8);
      *(bf16x8*)dst = v[q];
    }
    __syncthreads();
    #pragma unroll
    for (int kk = 0; kk < 64; kk += 32) {
      bf16x8 af[MI], bfr[NJ];
      #pragma unroll
      for (int i = 0; i < MI; ++i)
        af[i] = *(const bf16x8*)(lA + (wm + i * 16 + fr) * 72 + kk + kg);
      #pragma unroll
      for (int j = 0; j < NJ; ++j)
        bfr[j] = *(const bf16x8*)(lB + (wn + j * 16 + fr) * 72 + kk + kg);
      #pragma unroll
      for (int i = 0; i < MI; ++i)
        #pragma unroll
        for (int j = 0; j < NJ; ++j)
          acc[i][j] = __builtin_amdgcn_mfma_f32_16x16x32_bf16(af[i], bfr[j], acc[i][j], 0, 0, 0);
    }
  }

  const int rg = (lane >> 4) * 4;
  #pragma unroll
  for (int i = 0; i < MI; ++i) {
    int row = m0 + wm + i * 16 + rg;
    #pragma unroll
    for (int j = 0; j < NJ; ++j) {
      int col = n0 + wn + j * 16 + fr;
      if (col >= Nn) continue;
      #pragma unroll
      for (int r = 0; r < 4; ++r) {
        float v = acc[i][j][r];
        size_t idx = (size_t)(row + r) * Nn + col;
        if (EPI == 0) {
          if (OB) ((u16*)Cout)[idx] = f2bf(v);
          else    Cout[idx] = v;
        }
        else if (EPI == 1) Cout[idx] += v;
        else               Cout[idx] = v + bias[col] + pos[(size_t)((row + r) % L_) * Nn + col];
      }
    }
  }
}

// ---------------- LayerNorm (writes bf16 for GEMM A) ----------------
__global__ __launch_bounds__(384)
void k_ln(const float* __restrict__ x, const float* __restrict__ g,
          const float* __restrict__ bt, u16* __restrict__ h) {
  const int m = blockIdx.x, d = threadIdx.x;
  __shared__ float red[12];
  float v = x[(size_t)m * D_ + d];
  float s = v, s2 = v * v;
  #pragma unroll
  for (int o = 32; o > 0; o >>= 1) { s += __shfl_xor(s, o); s2 += __shfl_xor(s2, o); }
  int wid = d >> 6;
  if ((d & 63) == 0) { red[wid] = s; red[6 + wid] = s2; }
  __syncthreads();
  float ts = 0.f, ts2 = 0.f;
  #pragma unroll
  for (int w = 0; w < 6; ++w) { ts += red[w]; ts2 += red[6 + w]; }
  float mu = ts / (float)D_;
  float var = ts2 / (float)D_ - mu * mu;
  float rs = rsqrtf(var + 1e-5f);
  h[(size_t)m * D_ + d] = f2bf((v - mu) * rs * g[d] + bt[d]);
}

// ---------------- causal depthwise conv (K=4) + SiLU: bf16 in, bf16 out ----------------
// 4 channels per thread (ushort4 loads/stores)
__global__ __launch_bounds__(256)
void k_conv(const u16* __restrict__ xzb, const float* __restrict__ cw,
            const float* __restrict__ cb, u16* __restrict__ xcb) {
  int idx = blockIdx.x * 256 + threadIdx.x;   // over M_ * DI_/4
  if (idx >= M_ * (DI_ / 4)) return;
  int dq = idx % (DI_ / 4), m = idx / (DI_ / 4), l = m % L_;
  int di4 = dq * 4;
  const u16* base = xzb + (size_t)m * 1536 + di4;
  float xv[4][4];   // [tap][chan]
  #pragma unroll
  for (int t = 0; t < 4; ++t) {
    int back = 3 - t;
    u16x4 v = {};
    if (l >= back) v = *(const u16x4*)(base - (size_t)back * 1536);
    #pragma unroll
    for (int c = 0; c < 4; ++c) xv[t][c] = bf2f(v[c]);
  }
  f32x4 bv = *(const f32x4*)(cb + di4);
  u16x4 outv;
  #pragma unroll
  for (int c = 0; c < 4; ++c) {
    f32x4 w = *(const f32x4*)(cw + (size_t)(di4 + c) * 4);
    float acc = bv[c] + w[0] * xv[0][c] + w[1] * xv[1][c] + w[2] * xv[2][c] + w[3] * xv[3][c];
    float s = acc / (1.f + __expf(-acc));     // silu
    outv[c] = f2bf(s);
  }
  *(u16x4*)(xcb + (size_t)m * DI_ + di4) = outv;
}

// ---------------- dt = softplus(dbc[:, :24] @ dtp_w + dtp_b) ----------------
__global__ __launch_bounds__(256)
void k_dt(const float* __restrict__ dbc, const float* __restrict__ dtw,
          const float* __restrict__ dtb, float* __restrict__ dt) {
  const int m0 = blockIdx.x * 16;
  const int di = blockIdx.y * 256 + threadIdx.x;
  __shared__ float sd[16][25];
  #pragma unroll
  for (int q = 0; q < 2; ++q) {
    int id = threadIdx.x + q * 256;
    if (id < 16 * 24) {
      int r = id / 24, c = id % 24;
      sd[r][c] = dbc[(size_t)(m0 + r) * 56 + c];
    }
  }
  __syncthreads();
  float w[24];
  #pragma unroll
  for (int r = 0; r < 24; ++r) w[r] = dtw[r * DI_ + di];
  const float bv = dtb[di];
  #pragma unroll 4
  for (int mi = 0; mi < 16; ++mi) {
    float acc = bv;
    #pragma unroll
    for (int r = 0; r < 24; ++r) acc += sd[mi][r] * w[r];
    float e  = __expf(-fabsf(acc));
    float sp = fmaxf(acc, 0.f) + __logf(1.f + e);
    dt[(size_t)(m0 + mi) * DI_ + di] = sp;
  }
}

// ---------------- selective scan v2 (64 ch x 4 states), bf16 xc/z inputs ----------------
// grid (B_, DI_/64), block 256: thread = (di_local 0..63) x (nq 0..3), 4 states each
__global__ __launch_bounds__(256)
void k_scan(const float* __restrict__ dbc, const float* __restrict__ dt,
            const u16* __restrict__ xcb, const u16* __restrict__ xzb,
            const float* __restrict__ A_log, const float* __restrict__ Dsk,
            u16* __restrict__ yb) {
  const int b   = blockIdx.x;
  const int di0 = blockIdx.y * 64;
  const int tid = threadIdx.x;
  const int dil = tid >> 2, nq = tid & 3;
  const int di  = di0 + dil;
  __shared__ float sDT[2][SCH][64];
  __shared__ float sXC[2][SCH][64];
  __shared__ float sZ [2][SCH][64];
  __shared__ float sBC[2][SCH][32];
  __shared__ u16  sY [SCH][64];

  float Arow[4];
  #pragma unroll
  for (int n = 0; n < 4; ++n) Arow[n] = -__expf(A_log[di * NST + nq * 4 + n]);
  const float Dv = Dsk[di];
  float h[4] = {0.f, 0.f, 0.f, 0.f};
  const size_t mb = (size_t)b * L_;

  const int r16 = tid >> 4, c16 = (tid & 15) * 4;   // 64-wide arrays, 2 rounds of 16 rows
  const int r8  = tid >> 3, c8  = (tid & 7) * 4;    // 32-wide BC, 1 round of 32 rows

  f32x4 pDT[2], pBC;
  u16x4 pXC[2], pZ[2];
  auto issue = [&](int lb) {
    #pragma unroll
    for (int j = 0; j < 2; ++j) {
      int l = lb + r16 + j * 16;
      if (l < L_) {
        pDT[j] = *(const f32x4*)(dt + (mb + l) * DI_ + di0 + c16);
        pXC[j] = *(const u16x4*)(xcb + (mb + l) * DI_ + di0 + c16);
        pZ[j]  = *(const u16x4*)(xzb + (mb + l) * 1536 + DI_ + di0 + c16);
      } else { pDT[j] = {}; pXC[j] = u16x4{}; pZ[j] = u16x4{}; }
    }
    int l = lb + r8;
    if (l < L_) pBC = *(const f32x4*)(dbc + (mb + l) * 56 + 24 + c8);
    else        pBC = {};
  };
  auto store = [&](int buf) {
    #pragma unroll
    for (int j = 0; j < 2; ++j) {
      int row = r16 + j * 16;
      *(f32x4*)&sDT[buf][row][c16] = pDT[j];
      f32x4 xcv, zv;
      #pragma unroll
      for (int q = 0; q < 4; ++q) { xcv[q] = bf2f(pXC[j][q]); zv[q] = bf2f(pZ[j][q]); }
      *(f32x4*)&sXC[buf][row][c16] = xcv;
      *(f32x4*)&sZ [buf][row][c16] = zv;
    }
    *(f32x4*)&sBC[buf][r8][c8] = pBC;
  };

  issue(0); store(0); __syncthreads();
  const int nch = (L_ + SCH - 1) / SCH;   // 7
  for (int c = 0; c < nch; ++c) {
    const int lb = c * SCH;
    if (c + 1 < nch) issue(lb + SCH);     // global loads overlap compute below
    const int cur = c & 1;
    #pragma unroll 4
    for (int t = 0; t < SCH; ++t) {
      float dtc = sDT[cur][t][dil];
      float xcc = sXC[cur][t][dil];
      float dx = dtc * xcc;
      f32x4 Bv = *(const f32x4*)&sBC[cur][t][nq * 4];
      f32x4 Cv = *(const f32x4*)&sBC[cur][t][16 + nq * 4];
      float y = (nq == 0) ? Dv * xcc : 0.f;
      #pragma unroll
      for (int n = 0; n < 4; ++n) {
        float e = __expf(dtc * Arow[n]);
        h[n] = e * h[n] + dx * Bv[n];
        y += h[n] * Cv[n];
      }
      y += __shfl_xor(y, 1);
      y += __shfl_xor(y, 2);
      if (nq == 0) {
        float zc = sZ[cur][t][dil];
        float sz = zc / (1.f + __expf(-zc));
        sY[t][dil] = f2bf(y * sz);
      }
    }
    __syncthreads();
    #pragma unroll
    for (int j = 0; j < 4; ++j) {
      int id = tid + j * 256;
      int row = id >> 5, c2 = id & 31;
      int l = lb + row;
      if (l < L_)
        *((u32*)yb + ((mb + l) * DI_ + di0) / 2 + c2) = *((const u32*)&sY[row][0] + c2);
    }
    if (c + 1 < nch) store((c + 1) & 1);
    __syncthreads();
  }
}

// ---------------- final LN partial sums: grid (B_, 7), 28 rows each ----------------
__global__ __launch_bounds__(384)
void k_feat_part(const float* __restrict__ x, float* __restrict__ partial) {
  const int b = blockIdx.x, j = blockIdx.y, d = threadIdx.x;
  __shared__ float red[12];
  const int l0 = j * 28;
  float acc = 0.f;
  float v = x[((size_t)b * L_ + l0) * D_ + d];
  for (int l = l0; l < l0 + 28; ++l) {
    float vn = (l + 1 < l0 + 28) ? x[((size_t)b * L_ + l + 1) * D_ + d] : 0.f;
    float s = v, s2 = v * v;
    #pragma unroll
    for (int o = 32; o > 0; o >>= 1) { s += __shfl_xor(s, o); s2 += __shfl_xor(s2, o); }
    int wid = d >> 6;
    if ((d & 63) == 0) { red[wid] = s; red[6 + wid] = s2; }
    __syncthreads();
    float ts = 0.f, ts2 = 0.f;
    #pragma unroll
    for (int w = 0; w < 6; ++w) { ts += red[w]; ts2 += red[6 + w]; }
    float mu = ts * (1.f / (float)D_);
    float var = ts2 * (1.f / (float)D_) - mu * mu;
    acc += (v - mu) * rsqrtf(var + 1e-5f);
    __syncthreads();
    v = vn;
  }
  partial[((size_t)(b * 7 + j)) * D_ + d] = acc;
}

// ---------------- head (folds final-LN gamma/beta + mean) ----------------
__global__ __launch_bounds__(256)
void k_head(const float* __restrict__ partial, const float* __restrict__ g,
            const float* __restrict__ bt, const float* __restrict__ hw,
            const float* __restrict__ hb, float* __restrict__ out) {
  const int b = blockIdx.y;
  const int c = blockIdx.x * 256 + threadIdx.x;
  __shared__ float sf[D_];
  for (int i = threadIdx.x; i < D_; i += 256) {
    float s = 0.f;
    #pragma unroll
    for (int j = 0; j < 7; ++j) s += partial[((size_t)(b * 7 + j)) * D_ + i];
    sf[i] = g[i] * (s * (1.f / (float)L_)) + bt[i];
  }
  __syncthreads();
  if (c >= NC_) return;
  float acc = hb[c];
  for (int d = 0; d < D_; ++d) acc += sf[d] * hw[(size_t)d * NC_ + c];
  out[(size_t)b * NC_ + c] = acc;
}

// =====================================================================
extern "C" void kernel_launch(void* const* d_in, const int* in_sizes, int n_in,
                              void* d_out, int out_size, void* d_ws, size_t ws_size,
                              hipStream_t stream) {
  const float* x_in    = (const float*)d_in[0];
  const float* patch_w = (const float*)d_in[1];
  const float* patch_b = (const float*)d_in[2];
  const float* pos     = (const float*)d_in[3];
  const float* bn_g    = (const float*)d_in[4];
  const float* bn_b    = (const float*)d_in[5];
  const float* in_w    = (const float*)d_in[6];
  const float* conv_w  = (const float*)d_in[7];
  const float* conv_b  = (const float*)d_in[8];
  const float* xp_w    = (const float*)d_in[9];
  const float* dtp_w   = (const float*)d_in[10];
  const float* dtp_b   = (const float*)d_in[11];
  const float* A_log   = (const float*)d_in[12];
  const float* D_skip  = (const float*)d_in[13];
  const float* out_w   = (const float*)d_in[14];
  const float* norm_g  = (const float*)d_in[15];
  const float* norm_b  = (const float*)d_in[16];
  const float* head_w  = (const float*)d_in[17];
  const float* head_b  = (const float*)d_in[18];
  float* out = (float*)d_out;

  char* ws = (char*)d_ws;
  size_t off = 0;
  auto alloc = [&](size_t bytes) { size_t o = off; off += (bytes + 255) & ~(size_t)255; return o; };

  float* xbuf   = (float*)(ws + alloc((size_t)M_ * D_ * 4));
  u16*   hbuf   = (u16*)  (ws + alloc((size_t)M_ * D_ * 2));
  u16*   xzb    = (u16*)  (ws + alloc((size_t)M_ * 1536 * 2));
  u16*   xcbb   = (u16*)  (ws + alloc((size_t)M_ * DI_ * 2));
  float* dbcbuf = (float*)(ws + alloc((size_t)M_ * 56 * 4));
  float* dtbuf  = (float*)(ws + alloc((size_t)M_ * DI_ * 4));   // aliased as im2col before loop
  u16*   ybuf   = (u16*)  (ws + alloc((size_t)M_ * DI_ * 2));
  float* partial= (float*)(ws + alloc((size_t)B_ * 7 * D_ * 4));
  u16*   in_wT  = (u16*)  (ws + alloc((size_t)DEPTH * 1536 * D_ * 2));
  u16*   xp_wT  = (u16*)  (ws + alloc((size_t)DEPTH * 56 * DI_ * 2));
  u16*   out_wT = (u16*)  (ws + alloc((size_t)DEPTH * D_ * DI_ * 2));
  u16*   pw_b   = (u16*)  (ws + alloc((size_t)D_ * 768 * 2));
  u16*   im2col = (u16*)dtbuf;

  dim3 tb(32, 8);
  k_transpose_bf16<<<dim3(48, 12, DEPTH), tb, 0, stream>>>(in_w,  in_wT,  D_, 1536);
  k_transpose_bf16<<<dim3(2, 24, DEPTH),  tb, 0, stream>>>(xp_w,  xp_wT,  DI_, 56);
  k_transpose_bf16<<<dim3(12, 24, DEPTH), tb, 0, stream>>>(out_w, out_wT, DI_, D_);
  k_convert_bf16<<<(D_ * 768 + 255) / 256, 256, 0, stream>>>(patch_w, pw_b, D_ * 768);

  k_im2col<<<(M_ * 768 + 255) / 256, 256, 0, stream>>>(x_in, im2col);
  k_gemm<64,128,2,0><<<dim3(M_ / 64, 3), 256, 0, stream>>>(im2col, pw_b, xbuf, D_, 768, patch_b, pos);

  for (int dp = 0; dp < DEPTH; ++dp) {
    const u16* iwt = in_wT  + (size_t)dp * 1536 * D_;
    const u16* xwt = xp_wT  + (size_t)dp * 56 * DI_;
    const u16* owt = out_wT + (size_t)dp * D_ * DI_;
    k_ln<<<M_, 384, 0, stream>>>(xbuf, bn_g + dp * D_, bn_b + dp * D_, hbuf);
    k_gemm<128,128,0,1><<<dim3(M_ / 128, 12), 256, 0, stream>>>(hbuf, iwt, (float*)xzb, 1536, D_, nullptr, nullptr);
    k_conv<<<(M_ * (DI_ / 4) + 255) / 256, 256, 0, stream>>>(xzb, conv_w + (size_t)dp * DI_ * 4,
                                                             conv_b + dp * DI_, xcbb);
    k_gemm<32,64,0,0><<<dim3(M_ / 32, 1), 256, 0, stream>>>(xcbb, xwt, dbcbuf, 56, DI_, nullptr, nullptr);
    k_dt<<<dim3(M_ / 16, DI_ / 256), 256, 0, stream>>>(dbcbuf, dtp_w + (size_t)dp * R_ * DI_,
                                                       dtp_b + dp * DI_, dtbuf);
    k_scan<<<dim3(B_, DI_ / 64), 256, 0, stream>>>(dbcbuf, dtbuf, xcbb, xzb,
                                                   A_log + (size_t)dp * DI_ * NST,
                                                   D_skip + dp * DI_, ybuf);
    k_gemm<64,128,1,0><<<dim3(M_ / 64, 3), 256, 0, stream>>>(ybuf, owt, xbuf, D_, DI_, nullptr, nullptr);
  }

  k_feat_part<<<dim3(B_, 7), 384, 0, stream>>>(xbuf, partial);
  k_head<<<dim3((NC_ + 255) / 256, B_), 256, 0, stream>>>(partial, norm_g, norm_b, head_w, head_b, out);
}

// Round 6
// 1807.239 us; speedup vs baseline: 1.4356x; 1.0547x over previous
//
#include <hip/hip_runtime.h>
#include <math.h>

typedef short bf16x8 __attribute__((ext_vector_type(8)));
typedef float f32x4 __attribute__((ext_vector_type(4)));
typedef unsigned short u16;
typedef unsigned int u32;
typedef unsigned short u16x4 __attribute__((ext_vector_type(4)));

#define B_    32
#define D_    384
#define DEPTH 12
#define NST   16
#define DI_   768
#define R_    24
#define L_    196
#define NC_   1000
#define M_    (B_*L_)   // 6272
#define SEG   28        // scan segment length
#define NSEG  7         // L_ / SEG

__device__ __forceinline__ u16 f2bf(float f) {
  union { float f; unsigned u; } v; v.f = f;
  unsigned r = v.u + 0x7fffu + ((v.u >> 16) & 1u);
  return (u16)(r >> 16);
}
__device__ __forceinline__ float bf2f(u16 x) {
  union { unsigned u; float f; } v; v.u = ((unsigned)x) << 16;
  return v.f;
}

// ---------------- weight prep ----------------
__global__ void k_transpose_bf16(const float* __restrict__ in, u16* __restrict__ out,
                                 int R, int C) {
  __shared__ float tile[32][33];
  const size_t zoff = (size_t)blockIdx.z * R * C;
  in  += zoff; out += zoff;
  int c0 = blockIdx.x * 32, r0 = blockIdx.y * 32;
  int tx = threadIdx.x, ty = threadIdx.y;
  for (int i = ty; i < 32; i += 8) {
    int r = r0 + i, c = c0 + tx;
    tile[i][tx] = (r < R && c < C) ? in[(size_t)r * C + c] : 0.f;
  }
  __syncthreads();
  for (int i = ty; i < 32; i += 8) {
    int c = c0 + i, r = r0 + tx;
    if (c < C && r < R) out[(size_t)c * R + r] = f2bf(tile[tx][i]);
  }
}

__global__ void k_convert_bf16(const float* __restrict__ in, u16* __restrict__ out, int n) {
  int i = blockIdx.x * 256 + threadIdx.x;
  if (i < n) out[i] = f2bf(in[i]);
}

// ---------------- im2col for patch embed ----------------
__global__ void k_im2col(const float* __restrict__ x, u16* __restrict__ xcol) {
  int idx = blockIdx.x * 256 + threadIdx.x;     // over M_*768
  if (idx >= M_ * 768) return;
  int k = idx % 768, m = idx / 768;
  int b = m / L_, l = m % L_;
  int li = l / 14, lj = l % 14;
  int c = k / 256, r = k % 256;
  int i = r / 16, j = r % 16;
  int hh = li * 16 + i, ww = lj * 16 + j;
  xcol[idx] = f2bf(x[(((size_t)b * 3 + c) * 224 + hh) * 224 + ww]);
}

// ---------------- GEMM: C(MxN) = A(MxK,bf16) * BT(NxK,bf16)^T ----------------
// EPI: 0 = store, 1 = add (residual), 2 = store + bias[col] + pos[(row%L)*N+col]
// OB:  1 = store bf16 (u16) instead of f32 (EPI==0 only)
template<int BM, int BN, int EPI, int OB>
__global__ __launch_bounds__(256)
void k_gemm(const u16* __restrict__ A, const u16* __restrict__ BT,
            float* __restrict__ Cout, int Nn, int Kk,
            const float* __restrict__ bias, const float* __restrict__ pos) {
  const int m0 = blockIdx.x * BM;
  const int n0 = blockIdx.y * BN;
  __shared__ u16 lA[BM * 72];
  __shared__ u16 lB[BN * 72];
  const int tid  = threadIdx.x;
  const int wave = tid >> 6, lane = tid & 63;
  const int wm = (wave >> 1) * (BM / 2), wn = (wave & 1) * (BN / 2);
  constexpr int MI = BM / 32, NJ = BN / 32;
  constexpr int NV = (BM + BN) / 32;     // bf16x8 loads per thread per k-chunk
  f32x4 acc[MI][NJ] = {};
  const int fr = lane & 15, kg = (lane >> 4) * 8;

  for (int k0 = 0; k0 < Kk; k0 += 64) {
    bf16x8 v[NV];
    #pragma unroll
    for (int q = 0; q < NV; ++q) {
      int id = tid + q * 256;
      int row = id >> 3, vv = id & 7;
      bf16x8 t = {};
      if (row < BM) {
        t = *(const bf16x8*)(A + (size_t)(m0 + row) * Kk + k0 + vv * 8);
      } else {
        int br = n0 + row - BM;
        if (br < Nn) t = *(const bf16x8*)(BT + (size_t)br * Kk + k0 + vv * 8);
      }
      v[q] = t;
    }
    __syncthreads();
    #pragma unroll
    for (int q = 0; q < NV; ++q) {
      int id = tid + q * 256;
      int row = id >> 3, vv = id & 7;
      u16* dst = (row < BM) ? (lA + row * 72 + vv * 8) : (lB + (size_t)(row - BM) * 72 + vv * 8);
      *(bf16x8*)dst = v[q];
    }
    __syncthreads();
    #pragma unroll
    for (int kk = 0; kk < 64; kk += 32) {
      bf16x8 af[MI], bfr[NJ];
      #pragma unroll
      for (int i = 0; i < MI; ++i)
        af[i] = *(const bf16x8*)(lA + (wm + i * 16 + fr) * 72 + kk + kg);
      #pragma unroll
      for (int j = 0; j < NJ; ++j)
        bfr[j] = *(const bf16x8*)(lB + (wn + j * 16 + fr) * 72 + kk + kg);
      #pragma unroll
      for (int i = 0; i < MI; ++i)
        #pragma unroll
        for (int j = 0; j < NJ; ++j)
          acc[i][j] = __builtin_amdgcn_mfma_f32_16x16x32_bf16(af[i], bfr[j], acc[i][j], 0, 0, 0);
    }
  }

  const int rg = (lane >> 4) * 4;
  #pragma unroll
  for (int i = 0; i < MI; ++i) {
    int row = m0 + wm + i * 16 + rg;
    #pragma unroll
    for (int j = 0; j < NJ; ++j) {
      int col = n0 + wn + j * 16 + fr;
      if (col >= Nn) continue;
      #pragma unroll
      for (int r = 0; r < 4; ++r) {
        float v = acc[i][j][r];
        size_t idx = (size_t)(row + r) * Nn + col;
        if (EPI == 0) {
          if (OB) ((u16*)Cout)[idx] = f2bf(v);
          else    Cout[idx] = v;
        }
        else if (EPI == 1) Cout[idx] += v;
        else               Cout[idx] = v + bias[col] + pos[(size_t)((row + r) % L_) * Nn + col];
      }
    }
  }
}

// ---------------- LayerNorm (writes bf16 for GEMM A) ----------------
__global__ __launch_bounds__(384)
void k_ln(const float* __restrict__ x, const float* __restrict__ g,
          const float* __restrict__ bt, u16* __restrict__ h) {
  const int m = blockIdx.x, d = threadIdx.x;
  __shared__ float red[12];
  float v = x[(size_t)m * D_ + d];
  float s = v, s2 = v * v;
  #pragma unroll
  for (int o = 32; o > 0; o >>= 1) { s += __shfl_xor(s, o); s2 += __shfl_xor(s2, o); }
  int wid = d >> 6;
  if ((d & 63) == 0) { red[wid] = s; red[6 + wid] = s2; }
  __syncthreads();
  float ts = 0.f, ts2 = 0.f;
  #pragma unroll
  for (int w = 0; w < 6; ++w) { ts += red[w]; ts2 += red[6 + w]; }
  float mu = ts / (float)D_;
  float var = ts2 / (float)D_ - mu * mu;
  float rs = rsqrtf(var + 1e-5f);
  h[(size_t)m * D_ + d] = f2bf((v - mu) * rs * g[d] + bt[d]);
}

// ---------------- causal depthwise conv (K=4) + SiLU: bf16 in, bf16 out ----------------
__global__ __launch_bounds__(256)
void k_conv(const u16* __restrict__ xzb, const float* __restrict__ cw,
            const float* __restrict__ cb, u16* __restrict__ xcb) {
  int idx = blockIdx.x * 256 + threadIdx.x;   // over M_ * DI_/4
  if (idx >= M_ * (DI_ / 4)) return;
  int dq = idx % (DI_ / 4), m = idx / (DI_ / 4), l = m % L_;
  int di4 = dq * 4;
  const u16* base = xzb + (size_t)m * 1536 + di4;
  float xv[4][4];   // [tap][chan]
  #pragma unroll
  for (int t = 0; t < 4; ++t) {
    int back = 3 - t;
    u16x4 v = {};
    if (l >= back) v = *(const u16x4*)(base - (size_t)back * 1536);
    #pragma unroll
    for (int c = 0; c < 4; ++c) xv[t][c] = bf2f(v[c]);
  }
  f32x4 bv = *(const f32x4*)(cb + di4);
  u16x4 outv;
  #pragma unroll
  for (int c = 0; c < 4; ++c) {
    f32x4 w = *(const f32x4*)(cw + (size_t)(di4 + c) * 4);
    float acc = bv[c] + w[0] * xv[0][c] + w[1] * xv[1][c] + w[2] * xv[2][c] + w[3] * xv[3][c];
    float s = acc / (1.f + __expf(-acc));     // silu
    outv[c] = f2bf(s);
  }
  *(u16x4*)(xcb + (size_t)m * DI_ + di4) = outv;
}

// ---------------- dt = softplus(dbc[:, :24] @ dtp_w + dtp_b) ----------------
__global__ __launch_bounds__(256)
void k_dt(const float* __restrict__ dbc, const float* __restrict__ dtw,
          const float* __restrict__ dtb, float* __restrict__ dt) {
  const int m0 = blockIdx.x * 16;
  const int di = blockIdx.y * 256 + threadIdx.x;
  __shared__ float sd[16][25];
  #pragma unroll
  for (int q = 0; q < 2; ++q) {
    int id = threadIdx.x + q * 256;
    if (id < 16 * 24) {
      int r = id / 24, c = id % 24;
      sd[r][c] = dbc[(size_t)(m0 + r) * 56 + c];
    }
  }
  __syncthreads();
  float w[24];
  #pragma unroll
  for (int r = 0; r < 24; ++r) w[r] = dtw[r * DI_ + di];
  const float bv = dtb[di];
  #pragma unroll 4
  for (int mi = 0; mi < 16; ++mi) {
    float acc = bv;
    #pragma unroll
    for (int r = 0; r < 24; ++r) acc += sd[mi][r] * w[r];
    float e  = __expf(-fabsf(acc));
    float sp = fmaxf(acc, 0.f) + __logf(1.f + e);
    dt[(size_t)(m0 + mi) * DI_ + di] = sp;
  }
}

// ---------------- segmented scan pass A: local scan per 28-step segment ----------------
// grid (B_, DI_/64, NSEG), block 256 = 64 ch x 4 state-quads. h_in = 0.
// writes ypre (pre-gate y, f32), h_end & P_end per state.
__global__ __launch_bounds__(256)
void k_scan_part(const float* __restrict__ dbc, const float* __restrict__ dt,
                 const u16* __restrict__ xcb, const float* __restrict__ A_log,
                 const float* __restrict__ Dsk, float* __restrict__ ypre,
                 float* __restrict__ hend, float* __restrict__ pend) {
  const int b   = blockIdx.x;
  const int di0 = blockIdx.y * 64;
  const int s   = blockIdx.z;
  const int tid = threadIdx.x;
  const int dil = tid >> 2, nq = tid & 3;
  const int di  = di0 + dil;
  __shared__ float sDT[SEG][64];
  __shared__ float sXC[SEG][64];
  __shared__ float sBC[SEG][32];
  __shared__ float sY [SEG][64];

  float Arow[4];
  #pragma unroll
  for (int n = 0; n < 4; ++n) Arow[n] = -__expf(A_log[di * NST + nq * 4 + n]);
  const float Dv = Dsk[di];
  const size_t mb = (size_t)b * L_ + (size_t)s * SEG;

  // stage the whole segment
  {
    int r = tid >> 4, c = (tid & 15) * 4;
    #pragma unroll
    for (int j = 0; j < 2; ++j) {
      int row = r + j * 16;
      if (row < SEG) {
        *(f32x4*)&sDT[row][c] = *(const f32x4*)(dt + (mb + row) * DI_ + di0 + c);
        u16x4 xv = *(const u16x4*)(xcb + (mb + row) * DI_ + di0 + c);
        f32x4 xf;
        #pragma unroll
        for (int q = 0; q < 4; ++q) xf[q] = bf2f(xv[q]);
        *(f32x4*)&sXC[row][c] = xf;
      }
    }
    int r8 = tid >> 3, c8 = (tid & 7) * 4;
    if (r8 < SEG) *(f32x4*)&sBC[r8][c8] = *(const f32x4*)(dbc + (mb + r8) * 56 + 24 + c8);
  }
  __syncthreads();

  float h[4] = {0.f, 0.f, 0.f, 0.f};
  float P[4] = {1.f, 1.f, 1.f, 1.f};
  for (int t = 0; t < SEG; ++t) {
    float dtc = sDT[t][dil];
    float xcc = sXC[t][dil];
    float dx = dtc * xcc;
    f32x4 Bv = *(const f32x4*)&sBC[t][nq * 4];
    f32x4 Cv = *(const f32x4*)&sBC[t][16 + nq * 4];
    float y = (nq == 0) ? Dv * xcc : 0.f;
    #pragma unroll
    for (int n = 0; n < 4; ++n) {
      float e = __expf(dtc * Arow[n]);
      h[n] = e * h[n] + dx * Bv[n];
      P[n] *= e;
      y += h[n] * Cv[n];
    }
    y += __shfl_xor(y, 1);
    y += __shfl_xor(y, 2);
    if (nq == 0) sY[t][dil] = y;
  }
  {
    size_t sb = ((((size_t)s * B_ + b) * DI_) + di) * NST + nq * 4;
    *(f32x4*)(hend + sb) = f32x4{h[0], h[1], h[2], h[3]};
    *(f32x4*)(pend + sb) = f32x4{P[0], P[1], P[2], P[3]};
  }
  __syncthreads();
  #pragma unroll
  for (int j = 0; j < 2; ++j) {
    int id = tid + j * 256;
    if (id < SEG * 16) {
      int row = id >> 4, c = (id & 15) * 4;
      *(f32x4*)(ypre + (mb + row) * DI_ + di0 + c) = *(const f32x4*)&sY[row][c];
    }
  }
}

// ---------------- segmented scan pass B: carry-in correction + gate ----------------
// grid (B_, DI_/64, NSEG): y = (ypre + C · (P_running ⊙ h_in)) * silu(z), bf16 out
__global__ __launch_bounds__(256)
void k_scan_fix(const float* __restrict__ dbc, const float* __restrict__ dt,
                const u16* __restrict__ xzb, const float* __restrict__ A_log,
                const float* __restrict__ ypre, const float* __restrict__ hend,
                const float* __restrict__ pend, u16* __restrict__ yb) {
  const int b   = blockIdx.x;
  const int di0 = blockIdx.y * 64;
  const int s   = blockIdx.z;
  const int tid = threadIdx.x;
  const size_t mb = (size_t)b * L_ + (size_t)s * SEG;

  if (s == 0) {   // no carry-in: gate only, streaming
    #pragma unroll
    for (int j = 0; j < 2; ++j) {
      int id = tid + j * 256;
      if (id < SEG * 16) {
        int row = id >> 4, c = (id & 15) * 4;
        f32x4 yp = *(const f32x4*)(ypre + (mb + row) * DI_ + di0 + c);
        u16x4 zv = *(const u16x4*)(xzb + (mb + row) * 1536 + DI_ + di0 + c);
        u16x4 o;
        #pragma unroll
        for (int q = 0; q < 4; ++q) {
          float z = bf2f(zv[q]);
          o[q] = f2bf(yp[q] * z / (1.f + __expf(-z)));
        }
        *(u16x4*)(yb + (mb + row) * DI_ + di0 + c) = o;
      }
    }
    return;
  }

  const int dil = tid >> 2, nq = tid & 3;
  const int di  = di0 + dil;
  __shared__ float sDT[SEG][64];
  __shared__ float sZ [SEG][64];
  __shared__ float sYP[SEG][64];
  __shared__ float sC [SEG][16];
  __shared__ u16   sYO[SEG][64];

  float Arow[4];
  #pragma unroll
  for (int n = 0; n < 4; ++n) Arow[n] = -__expf(A_log[di * NST + nq * 4 + n]);

  // combine carry-in over previous segments: h_in = P_r ⊙ h_in + h_r
  f32x4 hin = {0.f, 0.f, 0.f, 0.f};
  for (int r = 0; r < s; ++r) {
    size_t sb = ((((size_t)r * B_ + b) * DI_) + di) * NST + nq * 4;
    f32x4 hr = *(const f32x4*)(hend + sb);
    f32x4 pr = *(const f32x4*)(pend + sb);
    #pragma unroll
    for (int q = 0; q < 4; ++q) hin[q] = pr[q] * hin[q] + hr[q];
  }

  // stage dt, z, ypre (64-wide) and C (16-wide)
  {
    int r = tid >> 4, c = (tid & 15) * 4;
    #pragma unroll
    for (int j = 0; j < 2; ++j) {
      int row = r + j * 16;
      if (row < SEG) {
        *(f32x4*)&sDT[row][c] = *(const f32x4*)(dt + (mb + row) * DI_ + di0 + c);
        *(f32x4*)&sYP[row][c] = *(const f32x4*)(ypre + (mb + row) * DI_ + di0 + c);
        u16x4 zv = *(const u16x4*)(xzb + (mb + row) * 1536 + DI_ + di0 + c);
        f32x4 zf;
        #pragma unroll
        for (int q = 0; q < 4; ++q) zf[q] = bf2f(zv[q]);
        *(f32x4*)&sZ[row][c] = zf;
      }
    }
    int rc = tid >> 2, cc = (tid & 3) * 4;
    if (rc < SEG) *(f32x4*)&sC[rc][cc] = *(const f32x4*)(dbc + (mb + rc) * 56 + 40 + cc);
  }
  __syncthreads();

  float hm[4] = {hin[0], hin[1], hin[2], hin[3]};
  for (int t = 0; t < SEG; ++t) {
    float dtc = sDT[t][dil];
    float d = 0.f;
    #pragma unroll
    for (int n = 0; n < 4; ++n) {
      float e = __expf(dtc * Arow[n]);
      hm[n] *= e;
      d += hm[n] * sC[t][nq * 4 + n];
    }
    d += __shfl_xor(d, 1);
    d += __shfl_xor(d, 2);
    if (nq == 0) {
      float z = sZ[t][dil];
      float y = (sYP[t][dil] + d) * z / (1.f + __expf(-z));
      sYO[t][dil] = f2bf(y);
    }
  }
  __syncthreads();
  #pragma unroll
  for (int j = 0; j < 4; ++j) {
    int id = tid + j * 256;
    if (id < SEG * 32) {
      int row = id >> 5, c2 = id & 31;
      *((u32*)yb + ((mb + row) * DI_ + di0) / 2 + c2) = *((const u32*)&sYO[row][0] + c2);
    }
  }
}

// ---------------- final LN partial sums: grid (B_, 7), 28 rows each ----------------
__global__ __launch_bounds__(384)
void k_feat_part(const float* __restrict__ x, float* __restrict__ partial) {
  const int b = blockIdx.x, j = blockIdx.y, d = threadIdx.x;
  __shared__ float red[12];
  const int l0 = j * 28;
  float acc = 0.f;
  float v = x[((size_t)b * L_ + l0) * D_ + d];
  for (int l = l0; l < l0 + 28; ++l) {
    float vn = (l + 1 < l0 + 28) ? x[((size_t)b * L_ + l + 1) * D_ + d] : 0.f;
    float s = v, s2 = v * v;
    #pragma unroll
    for (int o = 32; o > 0; o >>= 1) { s += __shfl_xor(s, o); s2 += __shfl_xor(s2, o); }
    int wid = d >> 6;
    if ((d & 63) == 0) { red[wid] = s; red[6 + wid] = s2; }
    __syncthreads();
    float ts = 0.f, ts2 = 0.f;
    #pragma unroll
    for (int w = 0; w < 6; ++w) { ts += red[w]; ts2 += red[6 + w]; }
    float mu = ts * (1.f / (float)D_);
    float var = ts2 * (1.f / (float)D_) - mu * mu;
    acc += (v - mu) * rsqrtf(var + 1e-5f);
    __syncthreads();
    v = vn;
  }
  partial[((size_t)(b * 7 + j)) * D_ + d] = acc;
}

// ---------------- head (folds final-LN gamma/beta + mean) ----------------
__global__ __launch_bounds__(256)
void k_head(const float* __restrict__ partial, const float* __restrict__ g,
            const float* __restrict__ bt, const float* __restrict__ hw,
            const float* __restrict__ hb, float* __restrict__ out) {
  const int b = blockIdx.y;
  const int c = blockIdx.x * 256 + threadIdx.x;
  __shared__ float sf[D_];
  for (int i = threadIdx.x; i < D_; i += 256) {
    float s = 0.f;
    #pragma unroll
    for (int j = 0; j < 7; ++j) s += partial[((size_t)(b * 7 + j)) * D_ + i];
    sf[i] = g[i] * (s * (1.f / (float)L_)) + bt[i];
  }
  __syncthreads();
  if (c >= NC_) return;
  float acc = hb[c];
  for (int d = 0; d < D_; ++d) acc += sf[d] * hw[(size_t)d * NC_ + c];
  out[(size_t)b * NC_ + c] = acc;
}

// =====================================================================
extern "C" void kernel_launch(void* const* d_in, const int* in_sizes, int n_in,
                              void* d_out, int out_size, void* d_ws, size_t ws_size,
                              hipStream_t stream) {
  const float* x_in    = (const float*)d_in[0];
  const float* patch_w = (const float*)d_in[1];
  const float* patch_b = (const float*)d_in[2];
  const float* pos     = (const float*)d_in[3];
  const float* bn_g    = (const float*)d_in[4];
  const float* bn_b    = (const float*)d_in[5];
  const float* in_w    = (const float*)d_in[6];
  const float* conv_w  = (const float*)d_in[7];
  const float* conv_b  = (const float*)d_in[8];
  const float* xp_w    = (const float*)d_in[9];
  const float* dtp_w   = (const float*)d_in[10];
  const float* dtp_b   = (const float*)d_in[11];
  const float* A_log   = (const float*)d_in[12];
  const float* D_skip  = (const float*)d_in[13];
  const float* out_w   = (const float*)d_in[14];
  const float* norm_g  = (const float*)d_in[15];
  const float* norm_b  = (const float*)d_in[16];
  const float* head_w  = (const float*)d_in[17];
  const float* head_b  = (const float*)d_in[18];
  float* out = (float*)d_out;

  char* ws = (char*)d_ws;
  size_t off = 0;
  auto alloc = [&](size_t bytes) { size_t o = off; off += (bytes + 255) & ~(size_t)255; return o; };

  float* xbuf   = (float*)(ws + alloc((size_t)M_ * D_ * 4));
  u16*   hbuf   = (u16*)  (ws + alloc((size_t)M_ * D_ * 2));
  u16*   xzb    = (u16*)  (ws + alloc((size_t)M_ * 1536 * 2));
  u16*   xcbb   = (u16*)  (ws + alloc((size_t)M_ * DI_ * 2));
  float* dbcbuf = (float*)(ws + alloc((size_t)M_ * 56 * 4));
  float* dtbuf  = (float*)(ws + alloc((size_t)M_ * DI_ * 4));   // aliased as im2col before loop
  u16*   ybuf   = (u16*)  (ws + alloc((size_t)M_ * DI_ * 2));
  float* ypre   = (float*)(ws + alloc((size_t)M_ * DI_ * 4));
  float* hend   = (float*)(ws + alloc((size_t)NSEG * B_ * DI_ * NST * 4));
  float* pend   = (float*)(ws + alloc((size_t)NSEG * B_ * DI_ * NST * 4));
  float* partial= (float*)(ws + alloc((size_t)B_ * 7 * D_ * 4));
  u16*   in_wT  = (u16*)  (ws + alloc((size_t)DEPTH * 1536 * D_ * 2));
  u16*   xp_wT  = (u16*)  (ws + alloc((size_t)DEPTH * 56 * DI_ * 2));
  u16*   out_wT = (u16*)  (ws + alloc((size_t)DEPTH * D_ * DI_ * 2));
  u16*   pw_b   = (u16*)  (ws + alloc((size_t)D_ * 768 * 2));
  u16*   im2col = (u16*)dtbuf;

  dim3 tb(32, 8);
  k_transpose_bf16<<<dim3(48, 12, DEPTH), tb, 0, stream>>>(in_w,  in_wT,  D_, 1536);
  k_transpose_bf16<<<dim3(2, 24, DEPTH),  tb, 0, stream>>>(xp_w,  xp_wT,  DI_, 56);
  k_transpose_bf16<<<dim3(12, 24, DEPTH), tb, 0, stream>>>(out_w, out_wT, DI_, D_);
  k_convert_bf16<<<(D_ * 768 + 255) / 256, 256, 0, stream>>>(patch_w, pw_b, D_ * 768);

  k_im2col<<<(M_ * 768 + 255) / 256, 256, 0, stream>>>(x_in, im2col);
  k_gemm<64,128,2,0><<<dim3(M_ / 64, 3), 256, 0, stream>>>(im2col, pw_b, xbuf, D_, 768, patch_b, pos);

  for (int dp = 0; dp < DEPTH; ++dp) {
    const u16* iwt = in_wT  + (size_t)dp * 1536 * D_;
    const u16* xwt = xp_wT  + (size_t)dp * 56 * DI_;
    const u16* owt = out_wT + (size_t)dp * D_ * DI_;
    const float* Al = A_log + (size_t)dp * DI_ * NST;
    k_ln<<<M_, 384, 0, stream>>>(xbuf, bn_g + dp * D_, bn_b + dp * D_, hbuf);
    k_gemm<128,128,0,1><<<dim3(M_ / 128, 12), 256, 0, stream>>>(hbuf, iwt, (float*)xzb, 1536, D_, nullptr, nullptr);
    k_conv<<<(M_ * (DI_ / 4) + 255) / 256, 256, 0, stream>>>(xzb, conv_w + (size_t)dp * DI_ * 4,
                                                             conv_b + dp * DI_, xcbb);
    k_gemm<32,64,0,0><<<dim3(M_ / 32, 1), 256, 0, stream>>>(xcbb, xwt, dbcbuf, 56, DI_, nullptr, nullptr);
    k_dt<<<dim3(M_ / 16, DI_ / 256), 256, 0, stream>>>(dbcbuf, dtp_w + (size_t)dp * R_ * DI_,
                                                       dtp_b + dp * DI_, dtbuf);
    k_scan_part<<<dim3(B_, DI_ / 64, NSEG), 256, 0, stream>>>(dbcbuf, dtbuf, xcbb, Al,
                                                              D_skip + dp * DI_, ypre, hend, pend);
    k_scan_fix<<<dim3(B_, DI_ / 64, NSEG), 256, 0, stream>>>(dbcbuf, dtbuf, xzb, Al,
                                                             ypre, hend, pend, ybuf);
    k_gemm<64,128,1,0><<<dim3(M_ / 64, 3), 256, 0, stream>>>(ybuf, owt, xbuf, D_, DI_, nullptr, nullptr);
  }

  k_feat_part<<<dim3(B_, 7), 384, 0, stream>>>(xbuf, partial);
  k_head<<<dim3((NC_ + 255) / 256, B_), 256, 0, stream>>>(partial, norm_g, norm_b, head_w, head_b, out);
}